// Round 15
// baseline (144.698 us; speedup 1.0000x reference)
//
#include <hip/hip_runtime.h>
#include <hip/hip_bf16.h>

#define NN 50000
#define EE 800000
#define DD 128
#define HH 2
#define CC 128
#define HC 256
#define EDD 8

#define LEAKY 0.2f
#define SMEPS 1e-16f
#define LNEPS 1e-5f

#define SCAN_B 196   // ceil(NN/256)
#define CONV_B 3125  // EE/256
#define K2_B   782   // ceil(NN/64)
#define NPAD   50176 // SCAN_B*256

// ---- ws byte offsets ----
#define HB_OFF    0u           // fp8 h interleaved [n][c][head]: NN*256B = 12,800,000
#define ASRC_OFF  12800000u    // f32 a_src: NN*2*4 = 400,000
#define ADST_OFF  13200000u    // f32 a_dst         = 400,000
#define CONST_OFF 13600000u    // 530 floats (pad 4096)
#define SD_OFF    13604096u    // int2 sd: EE*8     = 6,400,000 (d|rank|xcd in .y)
#define CNT8_OFF  20004096u    // int32 cnt8[8][NPAD] = 1,605,632
#define ROW_OFF   21609728u    // int32 rowstart (intra-block) = 200,704
#define BASE8_OFF 21810432u    // int32 base8[8][NPAD] (intra) = 1,605,632
#define PAY_OFF   23416064u    // int2 payload: EE*8 = 6,400,000
#define WBT_OFF   29816064u    // bf16 wbT[256][128] = 65,536
#define BSUM_OFF  29881600u    // int32 bsum: 256
// total ~29.9 MB

typedef __attribute__((ext_vector_type(8))) short short8v;   // 8 bf16 (4 VGPR)
typedef __attribute__((ext_vector_type(4))) float float4v;   // MFMA acc
typedef __attribute__((ext_vector_type(2))) int int2v;

__device__ __forceinline__ float bf2f(unsigned short v) {
  return __uint_as_float(((unsigned)v) << 16);
}
__device__ __forceinline__ unsigned short f2bf(float f) {
  __hip_bfloat16 b = __float2bfloat16(f);
  return *reinterpret_cast<unsigned short*>(&b);
}

// K1: prep. Block 0: attention-projection collapse -> consts.
// Blocks 1..128: W_lin -> bf16 transposed wbT. Blocks 129..324: zero cnt8.
__global__ __launch_bounds__(256) void k1_prep(const float* __restrict__ W_lin,
                                               const float* __restrict__ att_src,
                                               const float* __restrict__ att_dst,
                                               const float* __restrict__ W_le,
                                               const float* __restrict__ att_edge,
                                               const float* __restrict__ W_ep,
                                               const float* __restrict__ b_ep,
                                               float* __restrict__ consts,
                                               unsigned short* __restrict__ wbT,
                                               int* __restrict__ cnt8) {
  int b = blockIdx.x, tid = threadIdx.x;
  if (b == 0) {
    __shared__ float vlds[HH * DD];
    int h = tid >> 7, d = tid & 127;
    const float* as = att_src + h * CC;
    const float* ad = att_dst + h * CC;
    const float* ae = att_edge + h * CC;
    float us = 0.f, ud = 0.f, vv = 0.f;
    for (int c = 0; c < CC; ++c) {
      float wl = W_lin[d * HC + h * CC + c];
      float we = W_le[d * HC + h * CC + c];
      us += wl * as[c]; ud += wl * ad[c]; vv += we * ae[c];
    }
    consts[h * 128 + d] = us;
    consts[256 + h * 128 + d] = ud;
    vlds[h * 128 + d] = vv;
    __syncthreads();
    if (tid < 16) {
      int hh = tid >> 3, k = tid & 7;
      float w = 0.f;
      for (int dd2 = 0; dd2 < DD; ++dd2) w += W_ep[k * DD + dd2] * vlds[hh * 128 + dd2];
      consts[512 + hh * 8 + k] = w;
    }
    if (tid < 2) {
      float ce = 0.f;
      for (int dd2 = 0; dd2 < DD; ++dd2) ce += b_ep[dd2] * vlds[tid * 128 + dd2];
      consts[528 + tid] = ce;
    }
  } else if (b <= 128) {
    int i = (b - 1) * 256 + tid;           // i = k*256 + c, exactly 32768
    int k = i >> 8, c = i & 255;
    wbT[c * DD + k] = f2bf(W_lin[i]);
  } else {
    int n = (b - 129) * 256 + tid;         // exact: 196*256 = NPAD
#pragma unroll
    for (int r = 0; r < 8; ++r) cnt8[r * NPAD + n] = 0;
  }
}

// K2: fused MFMA projection + edge convert/histogram (data-independent halves;
// the latency-bound atomic histogram hides under the MFMA compute).
// Blocks 0..781: h = x @ W_lin (MFMA bf16), fused a_src/a_dst, fp8 epilogue.
// Blocks 782..3906: edge normalize + XCD-local histogram (workgroup-scope
// atomics -> issuing XCD's L2); sd.y packs d(16) | rank(13) | xcd(3).
__global__ __launch_bounds__(256) void k2_conv_mfma(const float* __restrict__ x,
                                                    const unsigned short* __restrict__ wbT,
                                                    const float* __restrict__ consts,
                                                    const int* __restrict__ ei_raw,
                                                    unsigned char* __restrict__ hbuf8,
                                                    float* __restrict__ a_src,
                                                    float* __restrict__ a_dst,
                                                    int* __restrict__ cnt8,
                                                    int2v* __restrict__ sd) {
  __shared__ unsigned short xs[64 * 256];   // 32KB (convert blocks don't touch)
  int tid = threadIdx.x;

  if (blockIdx.x >= K2_B) {
    int lane = tid & 63;
    int probe = ei_raw[2 * lane + 1];
    bool is64 = (__ballot(probe != 0) == 0ull);
    int xcd = __builtin_amdgcn_s_getreg((20) | (0 << 6) | ((32 - 1) << 11)) & 7;
    int i = (blockIdx.x - K2_B) * 256 + tid;   // exact: CONV_B*256 = EE
    int s, d;
    if (is64) { s = ei_raw[2 * i]; d = ei_raw[2 * (EE + i)]; }
    else      { s = ei_raw[i];     d = ei_raw[EE + i]; }
    int rk = __hip_atomic_fetch_add(&cnt8[xcd * NPAD + d], 1,
                                    __ATOMIC_RELAXED, __HIP_MEMORY_SCOPE_WORKGROUP);
    int2v v; v.x = s; v.y = d | (rk << 16) | (xcd << 29);
    sd[i] = v;
    return;
  }

  int n0 = blockIdx.x * 64;
  int r = tid >> 2, q = tid & 3;
  int n = n0 + r;
  bool valid = (n < NN);

  float xv[32];
  const float4* xp = (const float4*)(x + (size_t)n * DD + q * 32);
#pragma unroll
  for (int j = 0; j < 8; ++j) {
    float4 v = valid ? xp[j] : make_float4(0.f, 0.f, 0.f, 0.f);
    xv[j * 4 + 0] = v.x; xv[j * 4 + 1] = v.y; xv[j * 4 + 2] = v.z; xv[j * 4 + 3] = v.w;
  }
  float ps0 = 0.f, ps1 = 0.f, pd0 = 0.f, pd1 = 0.f;
#pragma unroll
  for (int j = 0; j < 32; j += 4) {
    float4 u0 = *(const float4*)(consts +   0 + q * 32 + j);
    float4 u1 = *(const float4*)(consts + 128 + q * 32 + j);
    float4 v0 = *(const float4*)(consts + 256 + q * 32 + j);
    float4 v1 = *(const float4*)(consts + 384 + q * 32 + j);
    ps0 += xv[j] * u0.x + xv[j+1] * u0.y + xv[j+2] * u0.z + xv[j+3] * u0.w;
    ps1 += xv[j] * u1.x + xv[j+1] * u1.y + xv[j+2] * u1.z + xv[j+3] * u1.w;
    pd0 += xv[j] * v0.x + xv[j+1] * v0.y + xv[j+2] * v0.z + xv[j+3] * v0.w;
    pd1 += xv[j] * v1.x + xv[j+1] * v1.y + xv[j+2] * v1.z + xv[j+3] * v1.w;
  }
#pragma unroll
  for (int off = 1; off < 4; off <<= 1) {
    ps0 += __shfl_xor(ps0, off); ps1 += __shfl_xor(ps1, off);
    pd0 += __shfl_xor(pd0, off); pd1 += __shfl_xor(pd1, off);
  }
  if (q == 0 && valid) {
    *(float2*)(a_src + n * 2) = make_float2(ps0, ps1);
    *(float2*)(a_dst + n * 2) = make_float2(pd0, pd1);
  }

#pragma unroll
  for (int ci = 0; ci < 4; ++ci) {
    union { short8v v; unsigned short u[8]; } pk;
#pragma unroll
    for (int j = 0; j < 8; ++j) pk.u[j] = f2bf(xv[ci * 8 + j]);
    unsigned byte = r * 256 + (q * 4 + ci) * 16;
    byte ^= (r & 7) << 4;
    *(short8v*)((char*)xs + byte) = pk.v;
  }

  int wave = tid >> 6, l = tid & 63;
  int wc = wave * 64;
  int lr = l & 15, lg = l >> 4;
  short8v bfr[4][4];
#pragma unroll
  for (int ct = 0; ct < 4; ++ct) {
    int col = wc + ct * 16 + lr;
#pragma unroll
    for (int kt = 0; kt < 4; ++kt)
      bfr[ct][kt] = *(const short8v*)(wbT + (size_t)col * DD + kt * 32 + lg * 8);
  }

  __syncthreads();

  float4v acc[4][4];
#pragma unroll
  for (int rt = 0; rt < 4; ++rt)
#pragma unroll
    for (int ct = 0; ct < 4; ++ct) acc[rt][ct] = (float4v){0.f, 0.f, 0.f, 0.f};

#pragma unroll
  for (int kt = 0; kt < 4; ++kt) {
    short8v afr[4];
#pragma unroll
    for (int rt = 0; rt < 4; ++rt) {
      int row = rt * 16 + lr;
      unsigned byte = row * 256 + kt * 64 + lg * 16;
      byte ^= (row & 7) << 4;
      afr[rt] = *(const short8v*)((const char*)xs + byte);
    }
#pragma unroll
    for (int rt = 0; rt < 4; ++rt)
#pragma unroll
      for (int ct = 0; ct < 4; ++ct)
        acc[rt][ct] = __builtin_amdgcn_mfma_f32_16x16x32_bf16(afr[rt], bfr[ct][kt], acc[rt][ct], 0, 0, 0);
  }

  // epilogue: acc -> LDS bf16 (interleaved, row-swizzled) -> fp8 pack -> 16B stores
  __syncthreads();
#pragma unroll
  for (int rt = 0; rt < 4; ++rt) {
#pragma unroll
    for (int j = 0; j < 4; ++j) {
      int row = rt * 16 + lg * 4 + j;
#pragma unroll
      for (int ct = 0; ct < 4; ++ct) {
        int col = wc + ct * 16 + lr;
        int idx2 = ((col & 127) << 1) | (col >> 7);
        unsigned o = (unsigned)idx2 * 2;
        unsigned byte = row * 512 + (o ^ ((((unsigned)(row & 7) ^ ((o >> 7) & 3))) << 4));
        *(unsigned short*)((char*)xs + byte) = f2bf(acc[rt][ct][j]);
      }
    }
  }
  __syncthreads();
  {
    int r2 = tid >> 2, q2 = tid & 3;
    int n2 = n0 + r2;
    if (n2 < NN) {
#pragma unroll
      for (int kk = 0; kk < 4; ++kk) {
        unsigned u4[4];
#pragma unroll
        for (int t2 = 0; t2 < 2; ++t2) {
          int k = kk * 2 + t2;
          unsigned o = q2 * 128 + k * 16;
          unsigned byte = r2 * 512 + (o ^ ((((unsigned)(r2 & 7) ^ ((o >> 7) & 3))) << 4));
          short8v v = *(short8v*)((char*)xs + byte);
          unsigned ua = __builtin_amdgcn_cvt_pk_fp8_f32(bf2f((unsigned short)v[0]), bf2f((unsigned short)v[1]), 0u, false);
          ua = __builtin_amdgcn_cvt_pk_fp8_f32(bf2f((unsigned short)v[2]), bf2f((unsigned short)v[3]), ua, true);
          unsigned ub = __builtin_amdgcn_cvt_pk_fp8_f32(bf2f((unsigned short)v[4]), bf2f((unsigned short)v[5]), 0u, false);
          ub = __builtin_amdgcn_cvt_pk_fp8_f32(bf2f((unsigned short)v[6]), bf2f((unsigned short)v[7]), ub, true);
          u4[t2 * 2] = ua; u4[t2 * 2 + 1] = ub;
        }
        uint4 w4 = make_uint4(u4[0], u4[1], u4[2], u4[3]);
        *(uint4*)(hbuf8 + (size_t)n2 * 256 + q2 * 64 + kk * 16) = w4;
      }
    }
  }
}

// K_scan1: per-block scan. Reads 8 XCD replicas, totals, intra-block exclusive
// scan -> rowstart (INTRA values); per-XCD running bases -> base8 (INTRA).
// Block sums -> bsum. Consumers reconstruct global offsets via LDS scan of bsum.
__global__ __launch_bounds__(256) void k_scan1(const int* __restrict__ cnt8,
                                               int* __restrict__ rowstart,
                                               int* __restrict__ base8,
                                               int* __restrict__ bsum) {
  __shared__ int sp[256];
  int t = threadIdx.x, b = blockIdx.x;
  int n = b * 256 + t;
  int c[8];
  int tot = 0;
#pragma unroll
  for (int r = 0; r < 8; ++r) {
    c[r] = (n < NN) ? cnt8[r * NPAD + n] : 0;
    tot += c[r];
  }
  sp[t] = tot;
  __syncthreads();
  for (int off = 1; off < 256; off <<= 1) {
    int u = (t >= off) ? sp[t - off] : 0;
    __syncthreads();
    sp[t] += u;
    __syncthreads();
  }
  int intra = sp[t] - tot;
  if (n < NN) {
    rowstart[n] = intra;
    int run = intra;
#pragma unroll
    for (int r = 0; r < 8; ++r) { base8[r * NPAD + n] = run; run += c[r]; }
  }
  if (t == 255) bsum[b] = sp[255];
}

// K34: edge pass, zero data atomics. Per-block LDS scan of bsum reconstructs
// the global block offset. pos = base8[xcd][d] + boff(d>>8) + rank.
__global__ __launch_bounds__(256) void k34_edge(const int2v* __restrict__ sd,
                                                const int* __restrict__ base8,
                                                const int* __restrict__ bsum,
                                                const float* __restrict__ edge_attr,
                                                const float* __restrict__ a_src,
                                                const float* __restrict__ a_dst,
                                                const float* __restrict__ consts,
                                                int2v* __restrict__ payload) {
  __shared__ int bs[256];
  int t = threadIdx.x;
  {
    int v = (t < SCAN_B) ? bsum[t] : 0;
    bs[t] = v;
    __syncthreads();
    for (int off = 1; off < 256; off <<= 1) {
      int u = (t >= off) ? bs[t - off] : 0;
      __syncthreads();
      bs[t] += u;
      __syncthreads();
    }
  }
  int e = blockIdx.x * 256 + t;   // grid exact: EE/256
  int2v sdv = sd[e];
  int s = sdv.x;
  unsigned y = (unsigned)sdv.y;
  int d = (int)(y & 0xFFFFu);
  int rk = (int)((y >> 16) & 0x1FFFu);
  int xcd = (int)(y >> 29);
  float4 ea0 = *(const float4*)(edge_attr + (size_t)e * 8);
  float4 ea1 = *(const float4*)(edge_attr + (size_t)e * 8 + 4);
  float2 asv = *(const float2*)(a_src + s * 2);
  float2 adv = *(const float2*)(a_dst + d * 2);
  const float* w0 = consts + 512;
  const float* w1 = consts + 520;
  float sc0 = asv.x + adv.x + consts[528]
            + ea0.x * w0[0] + ea0.y * w0[1] + ea0.z * w0[2] + ea0.w * w0[3]
            + ea1.x * w0[4] + ea1.y * w0[5] + ea1.z * w0[6] + ea1.w * w0[7];
  float sc1 = asv.y + adv.y + consts[529]
            + ea0.x * w1[0] + ea0.y * w1[1] + ea0.z * w1[2] + ea0.w * w1[3]
            + ea1.x * w1[4] + ea1.y * w1[5] + ea1.z * w1[6] + ea1.w * w1[7];
  sc0 = (sc0 >= 0.f) ? sc0 : LEAKY * sc0;
  sc1 = (sc1 >= 0.f) ? sc1 : LEAKY * sc1;
  float ex0 = __expf(sc0);
  float ex1 = __expf(sc1);
  unsigned pk = (unsigned)f2bf(ex0) | ((unsigned)f2bf(ex1) << 16);
  int blk = d >> 8;
  int boff = (blk == 0) ? 0 : bs[blk - 1];
  int pos = base8[xcd * NPAD + d] + boff + rk;
  int2v pv; pv.x = s << 8; pv.y = (int)pk;   // s<<8 = byte offset of fp8 row
  payload[pos] = pv;
}

// K5: wave per node. CSR walk, depth-4 batched pipeline, fp8 h decode.
// Per-block LDS scan of bsum reconstructs global rowstart offsets.
__global__ __launch_bounds__(256) void k5_fused(const int* __restrict__ rowstart,
                                                const int* __restrict__ bsum,
                                                const int2v* __restrict__ payload,
                                                const unsigned char* __restrict__ hb8,
                                                const float* __restrict__ x,
                                                const float* __restrict__ bias,
                                                const float* __restrict__ gamma,
                                                const float* __restrict__ beta,
                                                float* __restrict__ out) {
  __shared__ int bs[256];
  int t = threadIdx.x;
  {
    int v = (t < SCAN_B) ? bsum[t] : 0;
    bs[t] = v;
    __syncthreads();
    for (int off = 1; off < 256; off <<= 1) {
      int u = (t >= off) ? bs[t - off] : 0;
      __syncthreads();
      bs[t] += u;
      __syncthreads();
    }
  }
  int n = blockIdx.x * 4 + (t >> 6);      // grid exact: NN/4 = 12500
  int lane = t & 63;
  int b0 = n >> 8;
  int p0i = rowstart[n] + ((b0 == 0) ? 0 : bs[b0 - 1]);
  int p1i;
  if (n + 1 == NN) p1i = EE;
  else {
    int b1 = (n + 1) >> 8;
    p1i = rowstart[n + 1] + ((b1 == 0) ? 0 : bs[b1 - 1]);
  }
  p0i = __builtin_amdgcn_readfirstlane(p0i);
  p1i = __builtin_amdgcn_readfirstlane(p1i);
  int len = p1i - p0i;
  int c0 = lane * 2;
  const int2v* pp = payload + p0i;
  float a00 = 0.f, a01 = 0.f, a10 = 0.f, a11 = 0.f, se0 = 0.f, se1 = 0.f;

#define K5_LD(soff) (*(const unsigned*)(hb8 + (size_t)(unsigned)(soff) + lane * 4))
#define K5_ACC(pl, w) { \
    float ex0 = bf2f((unsigned short)((unsigned)(pl).y & 0xffffu)); \
    float ex1 = bf2f((unsigned short)(((unsigned)(pl).y) >> 16)); \
    a00 = fmaf(ex0, __builtin_amdgcn_cvt_f32_fp8((int)(w), 0), a00); \
    a01 = fmaf(ex1, __builtin_amdgcn_cvt_f32_fp8((int)(w), 1), a01); \
    a10 = fmaf(ex0, __builtin_amdgcn_cvt_f32_fp8((int)(w), 2), a10); \
    a11 = fmaf(ex1, __builtin_amdgcn_cvt_f32_fp8((int)(w), 3), a11); \
    se0 += ex0; se1 += ex1; }

  if (len > 0) {
    int2v p0 = pp[0];
    int2v p1 = (len > 1) ? pp[1] : p0;
    int2v p2 = (len > 2) ? pp[2] : p0;
    int2v p3 = (len > 3) ? pp[3] : p0;
    unsigned h0 = K5_LD(p0.x), h1 = K5_LD(p1.x), h2 = K5_LD(p2.x), h3 = K5_LD(p3.x);
    int i = 0;
    for (; i + 7 < len; i += 4) {
      int2v q0 = pp[i + 4], q1 = pp[i + 5], q2 = pp[i + 6], q3 = pp[i + 7];
      unsigned g0 = K5_LD(q0.x), g1 = K5_LD(q1.x), g2 = K5_LD(q2.x), g3 = K5_LD(q3.x);
      K5_ACC(p0, h0); K5_ACC(p1, h1); K5_ACC(p2, h2); K5_ACC(p3, h3);
      p0 = q0; p1 = q1; p2 = q2; p3 = q3;
      h0 = g0; h1 = g1; h2 = g2; h3 = g3;
    }
    int r = len - i;           // 1..7
    K5_ACC(p0, h0);
    if (r > 1) K5_ACC(p1, h1);
    if (r > 2) K5_ACC(p2, h2);
    if (r > 3) K5_ACC(p3, h3);
    if (r > 4) {
      int rem = r - 4;         // 1..3
      int2v q0 = pp[i + 4];
      int2v q1 = (rem > 1) ? pp[i + 5] : q0;
      int2v q2 = (rem > 2) ? pp[i + 6] : q0;
      unsigned g0 = K5_LD(q0.x), g1 = K5_LD(q1.x), g2 = K5_LD(q2.x);
      K5_ACC(q0, g0);
      if (rem > 1) K5_ACC(q1, g1);
      if (rem > 2) K5_ACC(q2, g2);
    }
  }
#undef K5_LD
#undef K5_ACC

  float inv0 = 0.5f / (se0 + SMEPS);
  float inv1 = 0.5f / (se1 + SMEPS);
  float2 xv = *(const float2*)(x + (size_t)n * DD + c0);
  float v0 = a00 * inv0 + a01 * inv1 + bias[c0] + xv.x;
  float v1 = a10 * inv0 + a11 * inv1 + bias[c0 + 1] + xv.y;
  float s = v0 + v1, ss = v0 * v0 + v1 * v1;
#pragma unroll
  for (int o = 32; o > 0; o >>= 1) {
    s += __shfl_xor(s, o);
    ss += __shfl_xor(ss, o);
  }
  float mu = s * (1.f / 128.f);
  float var = ss * (1.f / 128.f) - mu * mu;
  float rstd = rsqrtf(var + LNEPS);
  float2 ov;
  ov.x = (v0 - mu) * rstd * gamma[c0] + beta[c0];
  ov.y = (v1 - mu) * rstd * gamma[c0 + 1] + beta[c0 + 1];
  *(float2*)(out + (size_t)n * CC + c0) = ov;
}

extern "C" void kernel_launch(void* const* d_in, const int* in_sizes, int n_in,
                              void* d_out, int out_size, void* d_ws, size_t ws_size,
                              hipStream_t stream) {
  const float* x        = (const float*)d_in[0];
  const int*   ei_raw   = (const int*)d_in[1];
  const float* edge_attr= (const float*)d_in[2];
  const float* W_ep     = (const float*)d_in[3];
  const float* b_ep     = (const float*)d_in[4];
  const float* W_lin    = (const float*)d_in[5];
  const float* att_src  = (const float*)d_in[6];
  const float* att_dst  = (const float*)d_in[7];
  const float* W_le     = (const float*)d_in[8];
  const float* att_edge = (const float*)d_in[9];
  const float* bias_gat = (const float*)d_in[10];
  const float* ln_gamma = (const float*)d_in[11];
  const float* ln_beta  = (const float*)d_in[12];

  char* ws = (char*)d_ws;
  unsigned char* hbuf8 = (unsigned char*)(ws + HB_OFF);
  float*    a_src  = (float*)(ws + ASRC_OFF);
  float*    a_dst  = (float*)(ws + ADST_OFF);
  float*    consts = (float*)(ws + CONST_OFF);
  int2v*    sd     = (int2v*)(ws + SD_OFF);
  int*      cnt8   = (int*)(ws + CNT8_OFF);
  int*      rowst  = (int*)(ws + ROW_OFF);
  int*      base8  = (int*)(ws + BASE8_OFF);
  int2v*    payload= (int2v*)(ws + PAY_OFF);
  unsigned short* wbT = (unsigned short*)(ws + WBT_OFF);
  int*      bsum   = (int*)(ws + BSUM_OFF);

  k1_prep<<<325, 256, 0, stream>>>(W_lin, att_src, att_dst, W_le, att_edge, W_ep, b_ep,
                                   consts, wbT, cnt8);
  k2_conv_mfma<<<K2_B + CONV_B, 256, 0, stream>>>(x, wbT, consts, ei_raw, hbuf8,
                                                  a_src, a_dst, cnt8, sd);
  k_scan1<<<SCAN_B, 256, 0, stream>>>(cnt8, rowst, base8, bsum);
  k34_edge<<<CONV_B, 256, 0, stream>>>(sd, base8, bsum, edge_attr, a_src, a_dst, consts, payload);
  k5_fused<<<NN / 4, 256, 0, stream>>>(rowst, bsum, payload, hbuf8, x, bias_gat, ln_gamma, ln_beta, (float*)d_out);
}

// Round 16
// 141.326 us; speedup vs baseline: 1.0239x; 1.0239x over previous
//
#include <hip/hip_runtime.h>
#include <hip/hip_bf16.h>

#define NN 50000
#define EE 800000
#define DD 128
#define HH 2
#define CC 128
#define HC 256
#define EDD 8

#define LEAKY 0.2f
#define SMEPS 1e-16f
#define LNEPS 1e-5f

#define SCAN_B 196   // ceil(NN/256)
#define CONV_B 3125  // EE/256
#define K2_B   782   // ceil(NN/64)
#define NPAD   50176 // SCAN_B*256

// ---- ws byte offsets ----
#define HB_OFF    0u           // fp8 h interleaved [n][c][head]: NN*256B = 12,800,000
#define ASRC_OFF  12800000u    // f32 a_src: NN*2*4 = 400,000
#define ADST_OFF  13200000u    // f32 a_dst         = 400,000
#define CONST_OFF 13600000u    // 530 floats (pad 4096)
#define SD_OFF    13604096u    // int2 sd: EE*8     = 6,400,000 (d|rank|xcd in .y)
#define CNT8_OFF  20004096u    // int32 cnt8[8][NPAD] = 1,605,632
#define ROW_OFF   21609728u    // int32 rowstart (intra-block) = 200,704
#define BASE8_OFF 21810432u    // int32 base8[8][NPAD] (intra) = 1,605,632
#define PAY_OFF   23416064u    // int2 payload: EE*8 = 6,400,000
#define WBT_OFF   29816064u    // bf16 wbT[256][128] = 65,536
#define BSUM_OFF  29881600u    // int32 bsum: 256
// total ~29.9 MB

typedef __attribute__((ext_vector_type(8))) short short8v;   // 8 bf16 (4 VGPR)
typedef __attribute__((ext_vector_type(4))) float float4v;   // MFMA acc
typedef __attribute__((ext_vector_type(2))) int int2v;

__device__ __forceinline__ float bf2f(unsigned short v) {
  return __uint_as_float(((unsigned)v) << 16);
}
__device__ __forceinline__ unsigned short f2bf(float f) {
  __hip_bfloat16 b = __float2bfloat16(f);
  return *reinterpret_cast<unsigned short*>(&b);
}

// K1: prep. Block 0: attention-projection collapse -> consts.
// Blocks 1..128: W_lin -> bf16 transposed wbT. Blocks 129..324: zero cnt8.
__global__ __launch_bounds__(256) void k1_prep(const float* __restrict__ W_lin,
                                               const float* __restrict__ att_src,
                                               const float* __restrict__ att_dst,
                                               const float* __restrict__ W_le,
                                               const float* __restrict__ att_edge,
                                               const float* __restrict__ W_ep,
                                               const float* __restrict__ b_ep,
                                               float* __restrict__ consts,
                                               unsigned short* __restrict__ wbT,
                                               int* __restrict__ cnt8) {
  int b = blockIdx.x, tid = threadIdx.x;
  if (b == 0) {
    __shared__ float vlds[HH * DD];
    int h = tid >> 7, d = tid & 127;
    const float* as = att_src + h * CC;
    const float* ad = att_dst + h * CC;
    const float* ae = att_edge + h * CC;
    float us = 0.f, ud = 0.f, vv = 0.f;
    for (int c = 0; c < CC; ++c) {
      float wl = W_lin[d * HC + h * CC + c];
      float we = W_le[d * HC + h * CC + c];
      us += wl * as[c]; ud += wl * ad[c]; vv += we * ae[c];
    }
    consts[h * 128 + d] = us;
    consts[256 + h * 128 + d] = ud;
    vlds[h * 128 + d] = vv;
    __syncthreads();
    if (tid < 16) {
      int hh = tid >> 3, k = tid & 7;
      float w = 0.f;
      for (int dd2 = 0; dd2 < DD; ++dd2) w += W_ep[k * DD + dd2] * vlds[hh * 128 + dd2];
      consts[512 + hh * 8 + k] = w;
    }
    if (tid < 2) {
      float ce = 0.f;
      for (int dd2 = 0; dd2 < DD; ++dd2) ce += b_ep[dd2] * vlds[tid * 128 + dd2];
      consts[528 + tid] = ce;
    }
  } else if (b <= 128) {
    int i = (b - 1) * 256 + tid;           // i = k*256 + c, exactly 32768
    int k = i >> 8, c = i & 255;
    wbT[c * DD + k] = f2bf(W_lin[i]);
  } else {
    int n = (b - 129) * 256 + tid;         // exact: 196*256 = NPAD
#pragma unroll
    for (int r = 0; r < 8; ++r) cnt8[r * NPAD + n] = 0;
  }
}

// K2: fused MFMA projection + edge convert/histogram, roles INTERLEAVED
// (bid%5==0 -> MFMA tile, else -> convert group). 5 coprime 8 => both roles
// round-robin across all XCDs for the whole kernel, so the XCD-local atomic
// histogram saturates all 8 L2 atomic pipes while MFMA fills the compute pipes.
__global__ __launch_bounds__(256) void k2_conv_mfma(const float* __restrict__ x,
                                                    const unsigned short* __restrict__ wbT,
                                                    const float* __restrict__ consts,
                                                    const int* __restrict__ ei_raw,
                                                    unsigned char* __restrict__ hbuf8,
                                                    float* __restrict__ a_src,
                                                    float* __restrict__ a_dst,
                                                    int* __restrict__ cnt8,
                                                    int2v* __restrict__ sd) {
  __shared__ unsigned short xs[64 * 256];   // 32KB (convert blocks don't touch)
  int tid = threadIdx.x;
  int bid = blockIdx.x;

  if (bid % 5 != 0) {
    int conv_id = bid - 1 - bid / 5;       // dense index over non-multiples of 5
    if (conv_id >= CONV_B) return;
    int lane = tid & 63;
    int probe = ei_raw[2 * lane + 1];
    bool is64 = (__ballot(probe != 0) == 0ull);
    int xcd = __builtin_amdgcn_s_getreg((20) | (0 << 6) | ((32 - 1) << 11)) & 7;
    int i = conv_id * 256 + tid;           // exact: CONV_B*256 = EE
    int s, d;
    if (is64) { s = ei_raw[2 * i]; d = ei_raw[2 * (EE + i)]; }
    else      { s = ei_raw[i];     d = ei_raw[EE + i]; }
    int rk = __hip_atomic_fetch_add(&cnt8[xcd * NPAD + d], 1,
                                    __ATOMIC_RELAXED, __HIP_MEMORY_SCOPE_WORKGROUP);
    int2v v; v.x = s; v.y = d | (rk << 16) | (xcd << 29);
    sd[i] = v;
    return;
  }

  int n0 = (bid / 5) * 64;                 // MFMA tile id 0..781
  int r = tid >> 2, q = tid & 3;
  int n = n0 + r;
  bool valid = (n < NN);

  float xv[32];
  const float4* xp = (const float4*)(x + (size_t)n * DD + q * 32);
#pragma unroll
  for (int j = 0; j < 8; ++j) {
    float4 v = valid ? xp[j] : make_float4(0.f, 0.f, 0.f, 0.f);
    xv[j * 4 + 0] = v.x; xv[j * 4 + 1] = v.y; xv[j * 4 + 2] = v.z; xv[j * 4 + 3] = v.w;
  }
  float ps0 = 0.f, ps1 = 0.f, pd0 = 0.f, pd1 = 0.f;
#pragma unroll
  for (int j = 0; j < 32; j += 4) {
    float4 u0 = *(const float4*)(consts +   0 + q * 32 + j);
    float4 u1 = *(const float4*)(consts + 128 + q * 32 + j);
    float4 v0 = *(const float4*)(consts + 256 + q * 32 + j);
    float4 v1 = *(const float4*)(consts + 384 + q * 32 + j);
    ps0 += xv[j] * u0.x + xv[j+1] * u0.y + xv[j+2] * u0.z + xv[j+3] * u0.w;
    ps1 += xv[j] * u1.x + xv[j+1] * u1.y + xv[j+2] * u1.z + xv[j+3] * u1.w;
    pd0 += xv[j] * v0.x + xv[j+1] * v0.y + xv[j+2] * v0.z + xv[j+3] * v0.w;
    pd1 += xv[j] * v1.x + xv[j+1] * v1.y + xv[j+2] * v1.z + xv[j+3] * v1.w;
  }
#pragma unroll
  for (int off = 1; off < 4; off <<= 1) {
    ps0 += __shfl_xor(ps0, off); ps1 += __shfl_xor(ps1, off);
    pd0 += __shfl_xor(pd0, off); pd1 += __shfl_xor(pd1, off);
  }
  if (q == 0 && valid) {
    *(float2*)(a_src + n * 2) = make_float2(ps0, ps1);
    *(float2*)(a_dst + n * 2) = make_float2(pd0, pd1);
  }

#pragma unroll
  for (int ci = 0; ci < 4; ++ci) {
    union { short8v v; unsigned short u[8]; } pk;
#pragma unroll
    for (int j = 0; j < 8; ++j) pk.u[j] = f2bf(xv[ci * 8 + j]);
    unsigned byte = r * 256 + (q * 4 + ci) * 16;
    byte ^= (r & 7) << 4;
    *(short8v*)((char*)xs + byte) = pk.v;
  }

  int wave = tid >> 6, l = tid & 63;
  int wc = wave * 64;
  int lr = l & 15, lg = l >> 4;
  short8v bfr[4][4];
#pragma unroll
  for (int ct = 0; ct < 4; ++ct) {
    int col = wc + ct * 16 + lr;
#pragma unroll
    for (int kt = 0; kt < 4; ++kt)
      bfr[ct][kt] = *(const short8v*)(wbT + (size_t)col * DD + kt * 32 + lg * 8);
  }

  __syncthreads();

  float4v acc[4][4];
#pragma unroll
  for (int rt = 0; rt < 4; ++rt)
#pragma unroll
    for (int ct = 0; ct < 4; ++ct) acc[rt][ct] = (float4v){0.f, 0.f, 0.f, 0.f};

#pragma unroll
  for (int kt = 0; kt < 4; ++kt) {
    short8v afr[4];
#pragma unroll
    for (int rt = 0; rt < 4; ++rt) {
      int row = rt * 16 + lr;
      unsigned byte = row * 256 + kt * 64 + lg * 16;
      byte ^= (row & 7) << 4;
      afr[rt] = *(const short8v*)((const char*)xs + byte);
    }
#pragma unroll
    for (int rt = 0; rt < 4; ++rt)
#pragma unroll
      for (int ct = 0; ct < 4; ++ct)
        acc[rt][ct] = __builtin_amdgcn_mfma_f32_16x16x32_bf16(afr[rt], bfr[ct][kt], acc[rt][ct], 0, 0, 0);
  }

  // epilogue: acc -> LDS bf16 (interleaved, row-swizzled) -> fp8 pack -> 16B stores
  __syncthreads();
#pragma unroll
  for (int rt = 0; rt < 4; ++rt) {
#pragma unroll
    for (int j = 0; j < 4; ++j) {
      int row = rt * 16 + lg * 4 + j;
#pragma unroll
      for (int ct = 0; ct < 4; ++ct) {
        int col = wc + ct * 16 + lr;
        int idx2 = ((col & 127) << 1) | (col >> 7);
        unsigned o = (unsigned)idx2 * 2;
        unsigned byte = row * 512 + (o ^ ((((unsigned)(row & 7) ^ ((o >> 7) & 3))) << 4));
        *(unsigned short*)((char*)xs + byte) = f2bf(acc[rt][ct][j]);
      }
    }
  }
  __syncthreads();
  {
    int r2 = tid >> 2, q2 = tid & 3;
    int n2 = n0 + r2;
    if (n2 < NN) {
#pragma unroll
      for (int kk = 0; kk < 4; ++kk) {
        unsigned u4[4];
#pragma unroll
        for (int t2 = 0; t2 < 2; ++t2) {
          int k = kk * 2 + t2;
          unsigned o = q2 * 128 + k * 16;
          unsigned byte = r2 * 512 + (o ^ ((((unsigned)(r2 & 7) ^ ((o >> 7) & 3))) << 4));
          short8v v = *(short8v*)((char*)xs + byte);
          unsigned ua = __builtin_amdgcn_cvt_pk_fp8_f32(bf2f((unsigned short)v[0]), bf2f((unsigned short)v[1]), 0u, false);
          ua = __builtin_amdgcn_cvt_pk_fp8_f32(bf2f((unsigned short)v[2]), bf2f((unsigned short)v[3]), ua, true);
          unsigned ub = __builtin_amdgcn_cvt_pk_fp8_f32(bf2f((unsigned short)v[4]), bf2f((unsigned short)v[5]), 0u, false);
          ub = __builtin_amdgcn_cvt_pk_fp8_f32(bf2f((unsigned short)v[6]), bf2f((unsigned short)v[7]), ub, true);
          u4[t2 * 2] = ua; u4[t2 * 2 + 1] = ub;
        }
        uint4 w4 = make_uint4(u4[0], u4[1], u4[2], u4[3]);
        *(uint4*)(hbuf8 + (size_t)n2 * 256 + q2 * 64 + kk * 16) = w4;
      }
    }
  }
}

// K_scan1: per-block scan. Reads 8 XCD replicas, totals, intra-block exclusive
// scan -> rowstart (INTRA values); per-XCD running bases -> base8 (INTRA).
// Block sums -> bsum. Consumers reconstruct global offsets via LDS scan of bsum.
__global__ __launch_bounds__(256) void k_scan1(const int* __restrict__ cnt8,
                                               int* __restrict__ rowstart,
                                               int* __restrict__ base8,
                                               int* __restrict__ bsum) {
  __shared__ int sp[256];
  int t = threadIdx.x, b = blockIdx.x;
  int n = b * 256 + t;
  int c[8];
  int tot = 0;
#pragma unroll
  for (int r = 0; r < 8; ++r) {
    c[r] = (n < NN) ? cnt8[r * NPAD + n] : 0;
    tot += c[r];
  }
  sp[t] = tot;
  __syncthreads();
  for (int off = 1; off < 256; off <<= 1) {
    int u = (t >= off) ? sp[t - off] : 0;
    __syncthreads();
    sp[t] += u;
    __syncthreads();
  }
  int intra = sp[t] - tot;
  if (n < NN) {
    rowstart[n] = intra;
    int run = intra;
#pragma unroll
    for (int r = 0; r < 8; ++r) { base8[r * NPAD + n] = run; run += c[r]; }
  }
  if (t == 255) bsum[b] = sp[255];
}

// K34: edge pass, zero data atomics. Per-block LDS scan of bsum reconstructs
// the global block offset. pos = base8[xcd][d] + boff(d>>8) + rank.
__global__ __launch_bounds__(256) void k34_edge(const int2v* __restrict__ sd,
                                                const int* __restrict__ base8,
                                                const int* __restrict__ bsum,
                                                const float* __restrict__ edge_attr,
                                                const float* __restrict__ a_src,
                                                const float* __restrict__ a_dst,
                                                const float* __restrict__ consts,
                                                int2v* __restrict__ payload) {
  __shared__ int bs[256];
  int t = threadIdx.x;
  {
    int v = (t < SCAN_B) ? bsum[t] : 0;
    bs[t] = v;
    __syncthreads();
    for (int off = 1; off < 256; off <<= 1) {
      int u = (t >= off) ? bs[t - off] : 0;
      __syncthreads();
      bs[t] += u;
      __syncthreads();
    }
  }
  int e = blockIdx.x * 256 + t;   // grid exact: EE/256
  int2v sdv = sd[e];
  int s = sdv.x;
  unsigned y = (unsigned)sdv.y;
  int d = (int)(y & 0xFFFFu);
  int rk = (int)((y >> 16) & 0x1FFFu);
  int xcd = (int)(y >> 29);
  float4 ea0 = *(const float4*)(edge_attr + (size_t)e * 8);
  float4 ea1 = *(const float4*)(edge_attr + (size_t)e * 8 + 4);
  float2 asv = *(const float2*)(a_src + s * 2);
  float2 adv = *(const float2*)(a_dst + d * 2);
  const float* w0 = consts + 512;
  const float* w1 = consts + 520;
  float sc0 = asv.x + adv.x + consts[528]
            + ea0.x * w0[0] + ea0.y * w0[1] + ea0.z * w0[2] + ea0.w * w0[3]
            + ea1.x * w0[4] + ea1.y * w0[5] + ea1.z * w0[6] + ea1.w * w0[7];
  float sc1 = asv.y + adv.y + consts[529]
            + ea0.x * w1[0] + ea0.y * w1[1] + ea0.z * w1[2] + ea0.w * w1[3]
            + ea1.x * w1[4] + ea1.y * w1[5] + ea1.z * w1[6] + ea1.w * w1[7];
  sc0 = (sc0 >= 0.f) ? sc0 : LEAKY * sc0;
  sc1 = (sc1 >= 0.f) ? sc1 : LEAKY * sc1;
  float ex0 = __expf(sc0);
  float ex1 = __expf(sc1);
  unsigned pk = (unsigned)f2bf(ex0) | ((unsigned)f2bf(ex1) << 16);
  int blk = d >> 8;
  int boff = (blk == 0) ? 0 : bs[blk - 1];
  int pos = base8[xcd * NPAD + d] + boff + rk;
  int2v pv; pv.x = s << 8; pv.y = (int)pk;   // s<<8 = byte offset of fp8 row
  payload[pos] = pv;
}

// K5: wave per node. CSR walk, depth-4 batched pipeline, fp8 h decode.
// Per-block LDS scan of bsum reconstructs global rowstart offsets.
__global__ __launch_bounds__(256) void k5_fused(const int* __restrict__ rowstart,
                                                const int* __restrict__ bsum,
                                                const int2v* __restrict__ payload,
                                                const unsigned char* __restrict__ hb8,
                                                const float* __restrict__ x,
                                                const float* __restrict__ bias,
                                                const float* __restrict__ gamma,
                                                const float* __restrict__ beta,
                                                float* __restrict__ out) {
  __shared__ int bs[256];
  int t = threadIdx.x;
  {
    int v = (t < SCAN_B) ? bsum[t] : 0;
    bs[t] = v;
    __syncthreads();
    for (int off = 1; off < 256; off <<= 1) {
      int u = (t >= off) ? bs[t - off] : 0;
      __syncthreads();
      bs[t] += u;
      __syncthreads();
    }
  }
  int n = blockIdx.x * 4 + (t >> 6);      // grid exact: NN/4 = 12500
  int lane = t & 63;
  int b0 = n >> 8;
  int p0i = rowstart[n] + ((b0 == 0) ? 0 : bs[b0 - 1]);
  int p1i;
  if (n + 1 == NN) p1i = EE;
  else {
    int b1 = (n + 1) >> 8;
    p1i = rowstart[n + 1] + ((b1 == 0) ? 0 : bs[b1 - 1]);
  }
  p0i = __builtin_amdgcn_readfirstlane(p0i);
  p1i = __builtin_amdgcn_readfirstlane(p1i);
  int len = p1i - p0i;
  int c0 = lane * 2;
  const int2v* pp = payload + p0i;
  float a00 = 0.f, a01 = 0.f, a10 = 0.f, a11 = 0.f, se0 = 0.f, se1 = 0.f;

#define K5_LD(soff) (*(const unsigned*)(hb8 + (size_t)(unsigned)(soff) + lane * 4))
#define K5_ACC(pl, w) { \
    float ex0 = bf2f((unsigned short)((unsigned)(pl).y & 0xffffu)); \
    float ex1 = bf2f((unsigned short)(((unsigned)(pl).y) >> 16)); \
    a00 = fmaf(ex0, __builtin_amdgcn_cvt_f32_fp8((int)(w), 0), a00); \
    a01 = fmaf(ex1, __builtin_amdgcn_cvt_f32_fp8((int)(w), 1), a01); \
    a10 = fmaf(ex0, __builtin_amdgcn_cvt_f32_fp8((int)(w), 2), a10); \
    a11 = fmaf(ex1, __builtin_amdgcn_cvt_f32_fp8((int)(w), 3), a11); \
    se0 += ex0; se1 += ex1; }

  if (len > 0) {
    int2v p0 = pp[0];
    int2v p1 = (len > 1) ? pp[1] : p0;
    int2v p2 = (len > 2) ? pp[2] : p0;
    int2v p3 = (len > 3) ? pp[3] : p0;
    unsigned h0 = K5_LD(p0.x), h1 = K5_LD(p1.x), h2 = K5_LD(p2.x), h3 = K5_LD(p3.x);
    int i = 0;
    for (; i + 7 < len; i += 4) {
      int2v q0 = pp[i + 4], q1 = pp[i + 5], q2 = pp[i + 6], q3 = pp[i + 7];
      unsigned g0 = K5_LD(q0.x), g1 = K5_LD(q1.x), g2 = K5_LD(q2.x), g3 = K5_LD(q3.x);
      K5_ACC(p0, h0); K5_ACC(p1, h1); K5_ACC(p2, h2); K5_ACC(p3, h3);
      p0 = q0; p1 = q1; p2 = q2; p3 = q3;
      h0 = g0; h1 = g1; h2 = g2; h3 = g3;
    }
    int r = len - i;           // 1..7
    K5_ACC(p0, h0);
    if (r > 1) K5_ACC(p1, h1);
    if (r > 2) K5_ACC(p2, h2);
    if (r > 3) K5_ACC(p3, h3);
    if (r > 4) {
      int rem = r - 4;         // 1..3
      int2v q0 = pp[i + 4];
      int2v q1 = (rem > 1) ? pp[i + 5] : q0;
      int2v q2 = (rem > 2) ? pp[i + 6] : q0;
      unsigned g0 = K5_LD(q0.x), g1 = K5_LD(q1.x), g2 = K5_LD(q2.x);
      K5_ACC(q0, g0);
      if (rem > 1) K5_ACC(q1, g1);
      if (rem > 2) K5_ACC(q2, g2);
    }
  }
#undef K5_LD
#undef K5_ACC

  float inv0 = 0.5f / (se0 + SMEPS);
  float inv1 = 0.5f / (se1 + SMEPS);
  float2 xv = *(const float2*)(x + (size_t)n * DD + c0);
  float v0 = a00 * inv0 + a01 * inv1 + bias[c0] + xv.x;
  float v1 = a10 * inv0 + a11 * inv1 + bias[c0 + 1] + xv.y;
  float s = v0 + v1, ss = v0 * v0 + v1 * v1;
#pragma unroll
  for (int o = 32; o > 0; o >>= 1) {
    s += __shfl_xor(s, o);
    ss += __shfl_xor(ss, o);
  }
  float mu = s * (1.f / 128.f);
  float var = ss * (1.f / 128.f) - mu * mu;
  float rstd = rsqrtf(var + LNEPS);
  float2 ov;
  ov.x = (v0 - mu) * rstd * gamma[c0] + beta[c0];
  ov.y = (v1 - mu) * rstd * gamma[c0 + 1] + beta[c0 + 1];
  *(float2*)(out + (size_t)n * CC + c0) = ov;
}

extern "C" void kernel_launch(void* const* d_in, const int* in_sizes, int n_in,
                              void* d_out, int out_size, void* d_ws, size_t ws_size,
                              hipStream_t stream) {
  const float* x        = (const float*)d_in[0];
  const int*   ei_raw   = (const int*)d_in[1];
  const float* edge_attr= (const float*)d_in[2];
  const float* W_ep     = (const float*)d_in[3];
  const float* b_ep     = (const float*)d_in[4];
  const float* W_lin    = (const float*)d_in[5];
  const float* att_src  = (const float*)d_in[6];
  const float* att_dst  = (const float*)d_in[7];
  const float* W_le     = (const float*)d_in[8];
  const float* att_edge = (const float*)d_in[9];
  const float* bias_gat = (const float*)d_in[10];
  const float* ln_gamma = (const float*)d_in[11];
  const float* ln_beta  = (const float*)d_in[12];

  char* ws = (char*)d_ws;
  unsigned char* hbuf8 = (unsigned char*)(ws + HB_OFF);
  float*    a_src  = (float*)(ws + ASRC_OFF);
  float*    a_dst  = (float*)(ws + ADST_OFF);
  float*    consts = (float*)(ws + CONST_OFF);
  int2v*    sd     = (int2v*)(ws + SD_OFF);
  int*      cnt8   = (int*)(ws + CNT8_OFF);
  int*      rowst  = (int*)(ws + ROW_OFF);
  int*      base8  = (int*)(ws + BASE8_OFF);
  int2v*    payload= (int2v*)(ws + PAY_OFF);
  unsigned short* wbT = (unsigned short*)(ws + WBT_OFF);
  int*      bsum   = (int*)(ws + BSUM_OFF);

  k1_prep<<<325, 256, 0, stream>>>(W_lin, att_src, att_dst, W_le, att_edge, W_ep, b_ep,
                                   consts, wbT, cnt8);
  k2_conv_mfma<<<K2_B * 5, 256, 0, stream>>>(x, wbT, consts, ei_raw, hbuf8,
                                             a_src, a_dst, cnt8, sd);
  k_scan1<<<SCAN_B, 256, 0, stream>>>(cnt8, rowst, base8, bsum);
  k34_edge<<<CONV_B, 256, 0, stream>>>(sd, base8, bsum, edge_attr, a_src, a_dst, consts, payload);
  k5_fused<<<NN / 4, 256, 0, stream>>>(rowst, bsum, payload, hbuf8, x, bias_gat, ln_gamma, ln_beta, (float*)d_out);
}

// Round 17
// 140.201 us; speedup vs baseline: 1.0321x; 1.0080x over previous
//
#include <hip/hip_runtime.h>
#include <hip/hip_bf16.h>

#define NN 50000
#define EE 800000
#define DD 128
#define HH 2
#define CC 128
#define HC 256
#define EDD 8

#define LEAKY 0.2f
#define SMEPS 1e-16f
#define LNEPS 1e-5f

#define SCAN_B 196   // ceil(NN/256)
#define CONV_B 3125  // EE/256
#define K2_B   782   // ceil(NN/64)
#define NPAD   50176 // SCAN_B*256

// ---- ws byte offsets ----
#define HB_OFF    0u           // fp8 h interleaved [n][c][head]: NN*256B = 12,800,000
#define ASRC_OFF  12800000u    // f32 a_src: NN*2*4 = 400,000
#define ADST_OFF  13200000u    // f32 a_dst         = 400,000
#define CONST_OFF 13600000u    // 530 floats (pad 4096)
#define SD_OFF    13604096u    // int2 sd: EE*8     = 6,400,000 (d|rank|xcd in .y)
#define CNT8_OFF  20004096u    // int32 cnt8[8][NPAD] = 1,605,632
#define ROW_OFF   21609728u    // int32 rowstart (intra-block) = 200,704
#define BASE8_OFF 21810432u    // int32 base8[8][NPAD] (intra) = 1,605,632
#define PAY_OFF   23416064u    // int2 payload: EE*8 = 6,400,000
#define WBT_OFF   29816064u    // bf16 wbT[256][128] = 65,536
#define BSUM_OFF  29881600u    // int32 bsum: 256
// total ~29.9 MB

typedef __attribute__((ext_vector_type(8))) short short8v;   // 8 bf16 (4 VGPR)
typedef __attribute__((ext_vector_type(4))) float float4v;   // MFMA acc
typedef __attribute__((ext_vector_type(2))) int int2v;

__device__ __forceinline__ float bf2f(unsigned short v) {
  return __uint_as_float(((unsigned)v) << 16);
}
__device__ __forceinline__ unsigned short f2bf(float f) {
  __hip_bfloat16 b = __float2bfloat16(f);
  return *reinterpret_cast<unsigned short*>(&b);
}

// K1: prep. Block 0: attention-projection collapse -> consts.
// Blocks 1..128: W_lin -> bf16 transposed wbT. Blocks 129..324: zero cnt8.
__global__ __launch_bounds__(256) void k1_prep(const float* __restrict__ W_lin,
                                               const float* __restrict__ att_src,
                                               const float* __restrict__ att_dst,
                                               const float* __restrict__ W_le,
                                               const float* __restrict__ att_edge,
                                               const float* __restrict__ W_ep,
                                               const float* __restrict__ b_ep,
                                               float* __restrict__ consts,
                                               unsigned short* __restrict__ wbT,
                                               int* __restrict__ cnt8) {
  int b = blockIdx.x, tid = threadIdx.x;
  if (b == 0) {
    __shared__ float vlds[HH * DD];
    int h = tid >> 7, d = tid & 127;
    const float* as = att_src + h * CC;
    const float* ad = att_dst + h * CC;
    const float* ae = att_edge + h * CC;
    float us = 0.f, ud = 0.f, vv = 0.f;
    for (int c = 0; c < CC; ++c) {
      float wl = W_lin[d * HC + h * CC + c];
      float we = W_le[d * HC + h * CC + c];
      us += wl * as[c]; ud += wl * ad[c]; vv += we * ae[c];
    }
    consts[h * 128 + d] = us;
    consts[256 + h * 128 + d] = ud;
    vlds[h * 128 + d] = vv;
    __syncthreads();
    if (tid < 16) {
      int hh = tid >> 3, k = tid & 7;
      float w = 0.f;
      for (int dd2 = 0; dd2 < DD; ++dd2) w += W_ep[k * DD + dd2] * vlds[hh * 128 + dd2];
      consts[512 + hh * 8 + k] = w;
    }
    if (tid < 2) {
      float ce = 0.f;
      for (int dd2 = 0; dd2 < DD; ++dd2) ce += b_ep[dd2] * vlds[tid * 128 + dd2];
      consts[528 + tid] = ce;
    }
  } else if (b <= 128) {
    int i = (b - 1) * 256 + tid;           // i = k*256 + c, exactly 32768
    int k = i >> 8, c = i & 255;
    wbT[c * DD + k] = f2bf(W_lin[i]);
  } else {
    int n = (b - 129) * 256 + tid;         // exact: 196*256 = NPAD
#pragma unroll
    for (int r = 0; r < 8; ++r) cnt8[r * NPAD + n] = 0;
  }
}

// K2: fused MFMA projection + edge convert/histogram, roles interleaved
// (bid%5==0 -> MFMA tile, else -> convert). LDS held to 16KB (two-half
// epilogue) so convert blocks co-reside densely and keep the atomic unit
// saturated while MFMA fills the compute pipes.
__global__ __launch_bounds__(256) void k2_conv_mfma(const float* __restrict__ x,
                                                    const unsigned short* __restrict__ wbT,
                                                    const float* __restrict__ consts,
                                                    const int* __restrict__ ei_raw,
                                                    unsigned char* __restrict__ hbuf8,
                                                    float* __restrict__ a_src,
                                                    float* __restrict__ a_dst,
                                                    int* __restrict__ cnt8,
                                                    int2v* __restrict__ sd) {
  __shared__ unsigned short xs[64 * 128];   // 16KB: staging AND per-half epilogue
  int tid = threadIdx.x;
  int bid = blockIdx.x;

  if (bid % 5 != 0) {
    int conv_id = bid - 1 - bid / 5;       // dense index over non-multiples of 5
    if (conv_id >= CONV_B) return;
    int lane = tid & 63;
    int probe = ei_raw[2 * lane + 1];
    bool is64 = (__ballot(probe != 0) == 0ull);
    int xcd = __builtin_amdgcn_s_getreg((20) | (0 << 6) | ((32 - 1) << 11)) & 7;
    int i = conv_id * 256 + tid;           // exact: CONV_B*256 = EE
    int s, d;
    if (is64) { s = ei_raw[2 * i]; d = ei_raw[2 * (EE + i)]; }
    else      { s = ei_raw[i];     d = ei_raw[EE + i]; }
    int rk = __hip_atomic_fetch_add(&cnt8[xcd * NPAD + d], 1,
                                    __ATOMIC_RELAXED, __HIP_MEMORY_SCOPE_WORKGROUP);
    int2v v; v.x = s; v.y = d | (rk << 16) | (xcd << 29);
    sd[i] = v;
    return;
  }

  int n0 = (bid / 5) * 64;                 // MFMA tile id 0..781
  int r = tid >> 2, q = tid & 3;
  int n = n0 + r;
  bool valid = (n < NN);

  float xv[32];
  const float4* xp = (const float4*)(x + (size_t)n * DD + q * 32);
#pragma unroll
  for (int j = 0; j < 8; ++j) {
    float4 v = valid ? xp[j] : make_float4(0.f, 0.f, 0.f, 0.f);
    xv[j * 4 + 0] = v.x; xv[j * 4 + 1] = v.y; xv[j * 4 + 2] = v.z; xv[j * 4 + 3] = v.w;
  }
  float ps0 = 0.f, ps1 = 0.f, pd0 = 0.f, pd1 = 0.f;
#pragma unroll
  for (int j = 0; j < 32; j += 4) {
    float4 u0 = *(const float4*)(consts +   0 + q * 32 + j);
    float4 u1 = *(const float4*)(consts + 128 + q * 32 + j);
    float4 v0 = *(const float4*)(consts + 256 + q * 32 + j);
    float4 v1 = *(const float4*)(consts + 384 + q * 32 + j);
    ps0 += xv[j] * u0.x + xv[j+1] * u0.y + xv[j+2] * u0.z + xv[j+3] * u0.w;
    ps1 += xv[j] * u1.x + xv[j+1] * u1.y + xv[j+2] * u1.z + xv[j+3] * u1.w;
    pd0 += xv[j] * v0.x + xv[j+1] * v0.y + xv[j+2] * v0.z + xv[j+3] * v0.w;
    pd1 += xv[j] * v1.x + xv[j+1] * v1.y + xv[j+2] * v1.z + xv[j+3] * v1.w;
  }
#pragma unroll
  for (int off = 1; off < 4; off <<= 1) {
    ps0 += __shfl_xor(ps0, off); ps1 += __shfl_xor(ps1, off);
    pd0 += __shfl_xor(pd0, off); pd1 += __shfl_xor(pd1, off);
  }
  if (q == 0 && valid) {
    *(float2*)(a_src + n * 2) = make_float2(ps0, ps1);
    *(float2*)(a_dst + n * 2) = make_float2(pd0, pd1);
  }

  // bf16-convert + swizzled LDS staging write (16KB)
#pragma unroll
  for (int ci = 0; ci < 4; ++ci) {
    union { short8v v; unsigned short u[8]; } pk;
#pragma unroll
    for (int j = 0; j < 8; ++j) pk.u[j] = f2bf(xv[ci * 8 + j]);
    unsigned byte = r * 256 + (q * 4 + ci) * 16;
    byte ^= (r & 7) << 4;
    *(short8v*)((char*)xs + byte) = pk.v;
  }

  int wave = tid >> 6, l = tid & 63;
  int wc = wave * 64;
  int lr = l & 15, lg = l >> 4;
  short8v bfr[4][4];
#pragma unroll
  for (int ct = 0; ct < 4; ++ct) {
    int col = wc + ct * 16 + lr;
#pragma unroll
    for (int kt = 0; kt < 4; ++kt)
      bfr[ct][kt] = *(const short8v*)(wbT + (size_t)col * DD + kt * 32 + lg * 8);
  }

  __syncthreads();

  float4v acc[4][4];
#pragma unroll
  for (int rt = 0; rt < 4; ++rt)
#pragma unroll
    for (int ct = 0; ct < 4; ++ct) acc[rt][ct] = (float4v){0.f, 0.f, 0.f, 0.f};

#pragma unroll
  for (int kt = 0; kt < 4; ++kt) {
    short8v afr[4];
#pragma unroll
    for (int rt = 0; rt < 4; ++rt) {
      int row = rt * 16 + lr;
      unsigned byte = row * 256 + kt * 64 + lg * 16;
      byte ^= (row & 7) << 4;
      afr[rt] = *(const short8v*)((const char*)xs + byte);
    }
#pragma unroll
    for (int rt = 0; rt < 4; ++rt)
#pragma unroll
      for (int ct = 0; ct < 4; ++ct)
        acc[rt][ct] = __builtin_amdgcn_mfma_f32_16x16x32_bf16(afr[rt], bfr[ct][kt], acc[rt][ct], 0, 0, 0);
  }

  // ---- epilogue in two 32-row halves (16KB reused): acc -> LDS bf16
  // (interleaved, row-swizzled) -> fp8 pack -> coalesced 16B stores ----
#pragma unroll
  for (int hf = 0; hf < 2; ++hf) {
    __syncthreads();   // staging reads (hf=0) / prior half's readback (hf=1) done
#pragma unroll
    for (int rt2 = 0; rt2 < 2; ++rt2) {
      int rt = hf * 2 + rt2;
#pragma unroll
      for (int j = 0; j < 4; ++j) {
        int lrow = rt2 * 16 + lg * 4 + j;          // 0..31 within half
#pragma unroll
        for (int ct = 0; ct < 4; ++ct) {
          int col = wc + ct * 16 + lr;
          int idx2 = ((col & 127) << 1) | (col >> 7);
          unsigned o = (unsigned)idx2 * 2;
          unsigned byte = lrow * 512 + (o ^ ((((unsigned)(lrow & 7) ^ ((o >> 7) & 3))) << 4));
          *(unsigned short*)((char*)xs + byte) = f2bf(acc[rt][ct][j]);
        }
      }
    }
    __syncthreads();
    {
      int lrow = tid >> 3, ch = tid & 7;           // row 0..31, 64B-bf16 chunk 0..7
      int n2 = n0 + hf * 32 + lrow;
      if (n2 < NN) {
        unsigned u[8];
#pragma unroll
        for (int t2 = 0; t2 < 4; ++t2) {
          unsigned o = ch * 64 + t2 * 16;
          unsigned byte = lrow * 512 + (o ^ ((((unsigned)(lrow & 7) ^ ((o >> 7) & 3))) << 4));
          short8v v = *(short8v*)((char*)xs + byte);
          unsigned ua = __builtin_amdgcn_cvt_pk_fp8_f32(bf2f((unsigned short)v[0]), bf2f((unsigned short)v[1]), 0u, false);
          ua = __builtin_amdgcn_cvt_pk_fp8_f32(bf2f((unsigned short)v[2]), bf2f((unsigned short)v[3]), ua, true);
          unsigned ub = __builtin_amdgcn_cvt_pk_fp8_f32(bf2f((unsigned short)v[4]), bf2f((unsigned short)v[5]), 0u, false);
          ub = __builtin_amdgcn_cvt_pk_fp8_f32(bf2f((unsigned short)v[6]), bf2f((unsigned short)v[7]), ub, true);
          u[t2 * 2] = ua; u[t2 * 2 + 1] = ub;
        }
        *(uint4*)(hbuf8 + (size_t)n2 * 256 + ch * 32)      = make_uint4(u[0], u[1], u[2], u[3]);
        *(uint4*)(hbuf8 + (size_t)n2 * 256 + ch * 32 + 16) = make_uint4(u[4], u[5], u[6], u[7]);
      }
    }
  }
}

// K_scan1: per-block scan. Reads 8 XCD replicas, totals, intra-block exclusive
// scan -> rowstart (INTRA values); per-XCD running bases -> base8 (INTRA).
// Block sums -> bsum. Consumers reconstruct global offsets via LDS scan of bsum.
__global__ __launch_bounds__(256) void k_scan1(const int* __restrict__ cnt8,
                                               int* __restrict__ rowstart,
                                               int* __restrict__ base8,
                                               int* __restrict__ bsum) {
  __shared__ int sp[256];
  int t = threadIdx.x, b = blockIdx.x;
  int n = b * 256 + t;
  int c[8];
  int tot = 0;
#pragma unroll
  for (int r = 0; r < 8; ++r) {
    c[r] = (n < NN) ? cnt8[r * NPAD + n] : 0;
    tot += c[r];
  }
  sp[t] = tot;
  __syncthreads();
  for (int off = 1; off < 256; off <<= 1) {
    int u = (t >= off) ? sp[t - off] : 0;
    __syncthreads();
    sp[t] += u;
    __syncthreads();
  }
  int intra = sp[t] - tot;
  if (n < NN) {
    rowstart[n] = intra;
    int run = intra;
#pragma unroll
    for (int r = 0; r < 8; ++r) { base8[r * NPAD + n] = run; run += c[r]; }
  }
  if (t == 255) bsum[b] = sp[255];
}

// K34: edge pass, zero data atomics. Per-block LDS scan of bsum reconstructs
// the global block offset. pos = base8[xcd][d] + boff(d>>8) + rank.
__global__ __launch_bounds__(256) void k34_edge(const int2v* __restrict__ sd,
                                                const int* __restrict__ base8,
                                                const int* __restrict__ bsum,
                                                const float* __restrict__ edge_attr,
                                                const float* __restrict__ a_src,
                                                const float* __restrict__ a_dst,
                                                const float* __restrict__ consts,
                                                int2v* __restrict__ payload) {
  __shared__ int bs[256];
  int t = threadIdx.x;
  {
    int v = (t < SCAN_B) ? bsum[t] : 0;
    bs[t] = v;
    __syncthreads();
    for (int off = 1; off < 256; off <<= 1) {
      int u = (t >= off) ? bs[t - off] : 0;
      __syncthreads();
      bs[t] += u;
      __syncthreads();
    }
  }
  int e = blockIdx.x * 256 + t;   // grid exact: EE/256
  int2v sdv = sd[e];
  int s = sdv.x;
  unsigned y = (unsigned)sdv.y;
  int d = (int)(y & 0xFFFFu);
  int rk = (int)((y >> 16) & 0x1FFFu);
  int xcd = (int)(y >> 29);
  float4 ea0 = *(const float4*)(edge_attr + (size_t)e * 8);
  float4 ea1 = *(const float4*)(edge_attr + (size_t)e * 8 + 4);
  float2 asv = *(const float2*)(a_src + s * 2);
  float2 adv = *(const float2*)(a_dst + d * 2);
  const float* w0 = consts + 512;
  const float* w1 = consts + 520;
  float sc0 = asv.x + adv.x + consts[528]
            + ea0.x * w0[0] + ea0.y * w0[1] + ea0.z * w0[2] + ea0.w * w0[3]
            + ea1.x * w0[4] + ea1.y * w0[5] + ea1.z * w0[6] + ea1.w * w0[7];
  float sc1 = asv.y + adv.y + consts[529]
            + ea0.x * w1[0] + ea0.y * w1[1] + ea0.z * w1[2] + ea0.w * w1[3]
            + ea1.x * w1[4] + ea1.y * w1[5] + ea1.z * w1[6] + ea1.w * w1[7];
  sc0 = (sc0 >= 0.f) ? sc0 : LEAKY * sc0;
  sc1 = (sc1 >= 0.f) ? sc1 : LEAKY * sc1;
  float ex0 = __expf(sc0);
  float ex1 = __expf(sc1);
  unsigned pk = (unsigned)f2bf(ex0) | ((unsigned)f2bf(ex1) << 16);
  int blk = d >> 8;
  int boff = (blk == 0) ? 0 : bs[blk - 1];
  int pos = base8[xcd * NPAD + d] + boff + rk;
  int2v pv; pv.x = s << 8; pv.y = (int)pk;   // s<<8 = byte offset of fp8 row
  payload[pos] = pv;
}

// K5: wave per node. CSR walk, depth-4 batched pipeline, fp8 h decode.
// Per-block LDS scan of bsum reconstructs global rowstart offsets.
__global__ __launch_bounds__(256) void k5_fused(const int* __restrict__ rowstart,
                                                const int* __restrict__ bsum,
                                                const int2v* __restrict__ payload,
                                                const unsigned char* __restrict__ hb8,
                                                const float* __restrict__ x,
                                                const float* __restrict__ bias,
                                                const float* __restrict__ gamma,
                                                const float* __restrict__ beta,
                                                float* __restrict__ out) {
  __shared__ int bs[256];
  int t = threadIdx.x;
  {
    int v = (t < SCAN_B) ? bsum[t] : 0;
    bs[t] = v;
    __syncthreads();
    for (int off = 1; off < 256; off <<= 1) {
      int u = (t >= off) ? bs[t - off] : 0;
      __syncthreads();
      bs[t] += u;
      __syncthreads();
    }
  }
  int n = blockIdx.x * 4 + (t >> 6);      // grid exact: NN/4 = 12500
  int lane = t & 63;
  int b0 = n >> 8;
  int p0i = rowstart[n] + ((b0 == 0) ? 0 : bs[b0 - 1]);
  int p1i;
  if (n + 1 == NN) p1i = EE;
  else {
    int b1 = (n + 1) >> 8;
    p1i = rowstart[n + 1] + ((b1 == 0) ? 0 : bs[b1 - 1]);
  }
  p0i = __builtin_amdgcn_readfirstlane(p0i);
  p1i = __builtin_amdgcn_readfirstlane(p1i);
  int len = p1i - p0i;
  int c0 = lane * 2;
  const int2v* pp = payload + p0i;
  float a00 = 0.f, a01 = 0.f, a10 = 0.f, a11 = 0.f, se0 = 0.f, se1 = 0.f;

#define K5_LD(soff) (*(const unsigned*)(hb8 + (size_t)(unsigned)(soff) + lane * 4))
#define K5_ACC(pl, w) { \
    float ex0 = bf2f((unsigned short)((unsigned)(pl).y & 0xffffu)); \
    float ex1 = bf2f((unsigned short)(((unsigned)(pl).y) >> 16)); \
    a00 = fmaf(ex0, __builtin_amdgcn_cvt_f32_fp8((int)(w), 0), a00); \
    a01 = fmaf(ex1, __builtin_amdgcn_cvt_f32_fp8((int)(w), 1), a01); \
    a10 = fmaf(ex0, __builtin_amdgcn_cvt_f32_fp8((int)(w), 2), a10); \
    a11 = fmaf(ex1, __builtin_amdgcn_cvt_f32_fp8((int)(w), 3), a11); \
    se0 += ex0; se1 += ex1; }

  if (len > 0) {
    int2v p0 = pp[0];
    int2v p1 = (len > 1) ? pp[1] : p0;
    int2v p2 = (len > 2) ? pp[2] : p0;
    int2v p3 = (len > 3) ? pp[3] : p0;
    unsigned h0 = K5_LD(p0.x), h1 = K5_LD(p1.x), h2 = K5_LD(p2.x), h3 = K5_LD(p3.x);
    int i = 0;
    for (; i + 7 < len; i += 4) {
      int2v q0 = pp[i + 4], q1 = pp[i + 5], q2 = pp[i + 6], q3 = pp[i + 7];
      unsigned g0 = K5_LD(q0.x), g1 = K5_LD(q1.x), g2 = K5_LD(q2.x), g3 = K5_LD(q3.x);
      K5_ACC(p0, h0); K5_ACC(p1, h1); K5_ACC(p2, h2); K5_ACC(p3, h3);
      p0 = q0; p1 = q1; p2 = q2; p3 = q3;
      h0 = g0; h1 = g1; h2 = g2; h3 = g3;
    }
    int r = len - i;           // 1..7
    K5_ACC(p0, h0);
    if (r > 1) K5_ACC(p1, h1);
    if (r > 2) K5_ACC(p2, h2);
    if (r > 3) K5_ACC(p3, h3);
    if (r > 4) {
      int rem = r - 4;         // 1..3
      int2v q0 = pp[i + 4];
      int2v q1 = (rem > 1) ? pp[i + 5] : q0;
      int2v q2 = (rem > 2) ? pp[i + 6] : q0;
      unsigned g0 = K5_LD(q0.x), g1 = K5_LD(q1.x), g2 = K5_LD(q2.x);
      K5_ACC(q0, g0);
      if (rem > 1) K5_ACC(q1, g1);
      if (rem > 2) K5_ACC(q2, g2);
    }
  }
#undef K5_LD
#undef K5_ACC

  float inv0 = 0.5f / (se0 + SMEPS);
  float inv1 = 0.5f / (se1 + SMEPS);
  float2 xv = *(const float2*)(x + (size_t)n * DD + c0);
  float v0 = a00 * inv0 + a01 * inv1 + bias[c0] + xv.x;
  float v1 = a10 * inv0 + a11 * inv1 + bias[c0 + 1] + xv.y;
  float s = v0 + v1, ss = v0 * v0 + v1 * v1;
#pragma unroll
  for (int o = 32; o > 0; o >>= 1) {
    s += __shfl_xor(s, o);
    ss += __shfl_xor(ss, o);
  }
  float mu = s * (1.f / 128.f);
  float var = ss * (1.f / 128.f) - mu * mu;
  float rstd = rsqrtf(var + LNEPS);
  float2 ov;
  ov.x = (v0 - mu) * rstd * gamma[c0] + beta[c0];
  ov.y = (v1 - mu) * rstd * gamma[c0 + 1] + beta[c0 + 1];
  *(float2*)(out + (size_t)n * CC + c0) = ov;
}

extern "C" void kernel_launch(void* const* d_in, const int* in_sizes, int n_in,
                              void* d_out, int out_size, void* d_ws, size_t ws_size,
                              hipStream_t stream) {
  const float* x        = (const float*)d_in[0];
  const int*   ei_raw   = (const int*)d_in[1];
  const float* edge_attr= (const float*)d_in[2];
  const float* W_ep     = (const float*)d_in[3];
  const float* b_ep     = (const float*)d_in[4];
  const float* W_lin    = (const float*)d_in[5];
  const float* att_src  = (const float*)d_in[6];
  const float* att_dst  = (const float*)d_in[7];
  const float* W_le     = (const float*)d_in[8];
  const float* att_edge = (const float*)d_in[9];
  const float* bias_gat = (const float*)d_in[10];
  const float* ln_gamma = (const float*)d_in[11];
  const float* ln_beta  = (const float*)d_in[12];

  char* ws = (char*)d_ws;
  unsigned char* hbuf8 = (unsigned char*)(ws + HB_OFF);
  float*    a_src  = (float*)(ws + ASRC_OFF);
  float*    a_dst  = (float*)(ws + ADST_OFF);
  float*    consts = (float*)(ws + CONST_OFF);
  int2v*    sd     = (int2v*)(ws + SD_OFF);
  int*      cnt8   = (int*)(ws + CNT8_OFF);
  int*      rowst  = (int*)(ws + ROW_OFF);
  int*      base8  = (int*)(ws + BASE8_OFF);
  int2v*    payload= (int2v*)(ws + PAY_OFF);
  unsigned short* wbT = (unsigned short*)(ws + WBT_OFF);
  int*      bsum   = (int*)(ws + BSUM_OFF);

  k1_prep<<<325, 256, 0, stream>>>(W_lin, att_src, att_dst, W_le, att_edge, W_ep, b_ep,
                                   consts, wbT, cnt8);
  k2_conv_mfma<<<K2_B * 5, 256, 0, stream>>>(x, wbT, consts, ei_raw, hbuf8,
                                             a_src, a_dst, cnt8, sd);
  k_scan1<<<SCAN_B, 256, 0, stream>>>(cnt8, rowst, base8, bsum);
  k34_edge<<<CONV_B, 256, 0, stream>>>(sd, base8, bsum, edge_attr, a_src, a_dst, consts, payload);
  k5_fused<<<NN / 4, 256, 0, stream>>>(rowst, bsum, payload, hbuf8, x, bias_gat, ln_gamma, ln_beta, (float*)d_out);
}